// Round 10
// baseline (193.124 us; speedup 1.0000x reference)
//
#include <hip/hip_runtime.h>

// DirectionalConv3d: B=8, C_IN=C_OUT=64, T=R=32, CO=32
// v11: SINGLE fused kernel. The two-pass xq round-trip (33.5 MB write + read +
// a whole BW-bound dispatch) existed only for layout; v11 folds the fp32->bf16
// transpose INTO the t-ring staging (prep2's verified read/pack pattern,
// reg-staged into swizzled LDS), reads x directly, converts weights to bf16
// in-register per block. No workspace, no prep, no wprep.
//  grid 512 = 8 b x 32 rc-slices(32 rows) x 2 t-halves; block 256 thr =
//  4 waves (2 rh x 2 oh); wave = 16 rows x 32 o (f=2 LDS-read sharing),
//  4 independent MFMA chains. 4-slot ring of 96-row bf16 slabs (48 KB).
//  conv10's counted-barrier pipeline kept: ONE lgkmcnt(0)+s_barrier per iter,
//  global stores never drained, stage loads ordered by register deps only.

#define SB 32768   // spatial per batch (T*R*CO)
#define CIN 64
#define COUT 64

typedef short s16x8 __attribute__((ext_vector_type(8)));
typedef __bf16 bf16x8 __attribute__((ext_vector_type(8)));
typedef float f32x4 __attribute__((ext_vector_type(4)));

__device__ __forceinline__ unsigned f2bf(float f) {
    unsigned u = __float_as_uint(f);
    u += 0x7FFFu + ((u >> 16) & 1u);   // round-to-nearest-even
    return u >> 16;
}
__device__ __forceinline__ unsigned pk2(float lo, float hi) {
    return f2bf(lo) | (f2bf(hi) << 16);
}

// grid 512, block 256. bid: b = bid&7 (XCD-pinned), slice = (bid>>3)&31, th = bid>>8.
__global__ __launch_bounds__(256) void conv11_kernel(const float* __restrict__ x,
        const float* __restrict__ w0, const float* __restrict__ w1,
        const float* __restrict__ w2, const float* __restrict__ w3,
        const float* __restrict__ w4, const float* __restrict__ w5,
        const float* __restrict__ w6, float* __restrict__ out) {
    __shared__ uint4 ring[4][768];     // 4 slabs x 96 rows x 8 chunks = 48 KB
    int bid = blockIdx.x;
    int b = bid & 7;                   // batch = XCD (round-robin dispatch)
    int rc0 = ((bid >> 3) & 31) << 5;  // rc-slice base
    int t0 = (bid >> 8) << 4;          // t-half base: 0 or 16
    int tid = threadIdx.x;
    int lane = tid & 63;
    int wv = tid >> 6;                 // 0..3
    int lo = lane & 15;
    int quad = lane >> 4;
    int oh = wv & 1;                   // o-half (32 outputs)
    int rh = wv >> 1;                  // row-half (16 rows)
    const float* xb = x + (size_t)b * CIN * SB;

    // ---- B preload: fp32 w -> 28 bf16x8 frags in-register (112 VGPR) ----
    const float* wp[7] = {w0, w1, w2, w3, w4, w5, w6};
    bf16x8 bq[7][2][2];
#pragma unroll
    for (int tap = 0; tap < 7; ++tap)
#pragma unroll
        for (int ks = 0; ks < 2; ++ks)
#pragma unroll
            for (int nt = 0; nt < 2; ++nt) {
                const float* p = wp[tap] + (oh * 32 + nt * 16 + lo) * 64 + ks * 32 + quad * 8;
                float4 f0 = *(const float4*)p;
                float4 f1 = *(const float4*)(p + 4);
                uint4 v = make_uint4(pk2(f0.x, f0.y), pk2(f0.z, f0.w),
                                     pk2(f1.x, f1.y), pk2(f1.z, f1.w));
                bq[tap][ks][nt] = __builtin_bit_cast(bf16x8, v);
            }

    // lane geometry (t-invariant)
    int rc = rc0 + rh * 16 + lo;       // A-row rc in [0,1024)
    int rl = 32 + rh * 16 + lo;        // local slab row in [32,64)
    int r = rc >> 5;
    int c = rc & 31;
    bool okrm = (r > 0), okrp = (r < 31), okcm = (c > 0), okcp = (c < 31);

    // ---- staging: item = (2 rc-rows x 8 ch); thread owns item tid (+ item 256+tid if tid<128)
    // loads: 8 float2 per item along rc (8 x 64B-line groups per instr across the wave)
    int cg1 = tid & 7, s21 = tid >> 3;                 // item 1: rows 2*s21, +1
    int rx1 = rc0 - 32 + 2 * s21;
    rx1 = rx1 < 0 ? 0 : (rx1 > 1022 ? 1022 : rx1);     // even clamp; clamped rows masked-only
    int cg2 = tid & 7, s22 = 32 + (tid >> 3);          // item 2 (tid<128): rows 64..95
    int rx2 = rc0 - 32 + 2 * s22;
    rx2 = rx2 > 1022 ? 1022 : rx2;

    float2 va[8], vb[8];
    auto stage_load = [&](int ts) {
        const float* g1 = xb + (size_t)(cg1 * 8) * SB + ts * 1024 + rx1;
#pragma unroll
        for (int u = 0; u < 4; ++u) {
            va[u]     = *(const float2*)(g1 + (size_t)(2 * u) * SB);
            va[u + 4] = *(const float2*)(g1 + (size_t)(2 * u + 1) * SB);
        }
        if (tid < 128) {
            const float* g2 = xb + (size_t)(cg2 * 8) * SB + ts * 1024 + rx2;
#pragma unroll
            for (int u = 0; u < 4; ++u) {
                vb[u]     = *(const float2*)(g2 + (size_t)(2 * u) * SB);
                vb[u + 4] = *(const float2*)(g2 + (size_t)(2 * u + 1) * SB);
            }
        }
    };
    auto stage_write = [&](int ts) {
        int k = ts & 3;
        {
            int rw = 2 * s21;
            uint4 A = make_uint4(pk2(va[0].x, va[4].x), pk2(va[1].x, va[5].x),
                                 pk2(va[2].x, va[6].x), pk2(va[3].x, va[7].x));
            uint4 B = make_uint4(pk2(va[0].y, va[4].y), pk2(va[1].y, va[5].y),
                                 pk2(va[2].y, va[6].y), pk2(va[3].y, va[7].y));
            ring[k][rw * 8 + (cg1 ^ (rw & 7))] = A;
            ring[k][(rw + 1) * 8 + (cg1 ^ ((rw + 1) & 7))] = B;
        }
        if (tid < 128) {
            int rw = 2 * s22;
            uint4 A = make_uint4(pk2(vb[0].x, vb[4].x), pk2(vb[1].x, vb[5].x),
                                 pk2(vb[2].x, vb[6].x), pk2(vb[3].x, vb[7].x));
            uint4 B = make_uint4(pk2(vb[0].y, vb[4].y), pk2(vb[1].y, vb[5].y),
                                 pk2(vb[2].y, vb[6].y), pk2(vb[3].y, vb[7].y));
            ring[k][rw * 8 + (cg2 ^ (rw & 7))] = A;
            ring[k][(rw + 1) * 8 + (cg2 ^ ((rw + 1) & 7))] = B;
        }
    };

    const s16x8 zz = {0, 0, 0, 0, 0, 0, 0, 0};
    f32x4 aA0, aB0, aA1, aB1;          // 4 independent chains: [nt] x [ks]

    // one tap: 2 ds_read_b128 (shared by both nt tiles, f=2) + 4 MFMA
    auto tap_f = [&](const uint4* slab, const bf16x8 (&bt)[2][2], int d, bool ok) {
        int row = rl + d;                              // always in [0,96)
        s16x8 a0 = *((const s16x8*)slab + row * 8 + (quad ^ (row & 7)));
        s16x8 a1 = *((const s16x8*)slab + row * 8 + ((4 + quad) ^ (row & 7)));
        a0 = ok ? a0 : zz;
        a1 = ok ? a1 : zz;
        bf16x8 af0 = __builtin_bit_cast(bf16x8, a0);
        bf16x8 af1 = __builtin_bit_cast(bf16x8, a1);
        aA0 = __builtin_amdgcn_mfma_f32_16x16x32_bf16(af0, bt[0][0], aA0, 0, 0, 0);
        aB0 = __builtin_amdgcn_mfma_f32_16x16x32_bf16(af1, bt[1][0], aB0, 0, 0, 0);
        aA1 = __builtin_amdgcn_mfma_f32_16x16x32_bf16(af0, bt[0][1], aA1, 0, 0, 0);
        aB1 = __builtin_amdgcn_mfma_f32_16x16x32_bf16(af1, bt[1][1], aB1, 0, 0, 0);
    };

    // ---- prologue: stage slabs t0-1 (th=1 only), t0, t0+1 ----
    if (t0 > 0) { stage_load(t0 - 1); stage_write(t0 - 1); }
    stage_load(t0);     stage_write(t0);
    stage_load(t0 + 1); stage_write(t0 + 1);
    asm volatile("s_waitcnt lgkmcnt(0)" ::: "memory");
    __builtin_amdgcn_s_barrier();
    __builtin_amdgcn_sched_barrier(0);

    int smax = (t0 == 0) ? 16 : 31;    // highest slab this block ever reads
    for (int t = t0; t < t0 + 16; ++t) {
        bool pf = (t + 2 <= smax);
        if (pf) stage_load(t + 2);     // async: HBM/L3 latency hides under compute

        aA0 = (f32x4){0.f, 0.f, 0.f, 0.f};
        aB0 = (f32x4){0.f, 0.f, 0.f, 0.f};
        aA1 = (f32x4){0.f, 0.f, 0.f, 0.f};
        aB1 = (f32x4){0.f, 0.f, 0.f, 0.f};
        const uint4* s0 = &ring[t & 3][0];

        tap_f(s0, bq[0], 0, true);                             // self
        if (t > 0)  tap_f(&ring[(t - 1) & 3][0], bq[1], 0, true);   // t-1
        if (t < 31) tap_f(&ring[(t + 1) & 3][0], bq[2], 0, true);   // t+1
        tap_f(s0, bq[3], -32, okrm);                           // r-1
        tap_f(s0, bq[4], 32, okrp);                            // r+1
        tap_f(s0, bq[5], -1, okcm);                            // c-1
        tap_f(s0, bq[6], 1, okcp);                             // c+1

        // D layout: col(o) = lane&15, row = quad*4 + reg; stores never drained in-loop
        f32x4 o0 = aA0 + aB0;
        f32x4 o1 = aA1 + aB1;
        size_t ob = ((size_t)(b * COUT + oh * 32 + lo)) * SB
                  + (size_t)t * 1024 + rc0 + rh * 16 + quad * 4;
        *(f32x4*)(out + ob) = o0;                  // nt = 0
        *(f32x4*)(out + ob + (size_t)16 * SB) = o1;    // nt = 1 (o += 16)

        if (pf) stage_write(t + 2);    // slot (t+2)&3 = (t-2)&3: last read iter t-1 (barrier'd)

        asm volatile("s_waitcnt lgkmcnt(0)" ::: "memory");   // my ds ops retired
        __builtin_amdgcn_s_barrier();                        // publish slab t+2; close iter reads
        __builtin_amdgcn_sched_barrier(0);
    }
}

extern "C" void kernel_launch(void* const* d_in, const int* in_sizes, int n_in,
                              void* d_out, int out_size, void* d_ws, size_t ws_size,
                              hipStream_t stream) {
    const float* x = (const float*)d_in[0];
    const float* w0 = (const float*)d_in[1];
    const float* w1 = (const float*)d_in[2];
    const float* w2 = (const float*)d_in[3];
    const float* w3 = (const float*)d_in[4];
    const float* w4 = (const float*)d_in[5];
    const float* w5 = (const float*)d_in[6];
    const float* w6 = (const float*)d_in[7];
    float* out = (float*)d_out;
    (void)d_ws; (void)ws_size;

    conv11_kernel<<<512, 256, 0, stream>>>(x, w0, w1, w2, w3, w4, w5, w6, out);
}

// Round 11
// 191.163 us; speedup vs baseline: 1.0103x; 1.0103x over previous
//
#include <hip/hip_runtime.h>

// DirectionalConv3d: B=8, C_IN=C_OUT=64, T=R=32, CO=32
// v12: single fused kernel (conv11 geometry, FIXED schedule).
// conv11's 100us regression: stage_load(t+2) and stage_write(t+2) were in the
// SAME iteration -> every iteration's barrier chain contained a full HBM/L3
// round-trip (register dep va/vb). v12 splits them by a full iteration
// (T14 issue-early/write-late):
//   iter t: stage_write(t+2) [va/vb loaded in iter t-1, latency long covered]
//           stage_load(t+3)  [consumed next iter]
//           compute(t); store(t) [never drained]; lgkmcnt(0)+s_barrier.
//  grid 512 = 8 b x 32 rc-slices(32 rows) x 2 t-halves; block 256 thr =
//  4 waves (2 rh x 2 oh); wave = 16 rows x 32 o (f=2 LDS-read sharing),
//  4 independent MFMA chains. 4-slot ring of 96-row bf16 slabs (48 KB).
//  No workspace, no prep pass; weights converted in-register per block.

#define SB 32768   // spatial per batch (T*R*CO)
#define CIN 64
#define COUT 64

typedef short s16x8 __attribute__((ext_vector_type(8)));
typedef __bf16 bf16x8 __attribute__((ext_vector_type(8)));
typedef float f32x4 __attribute__((ext_vector_type(4)));

__device__ __forceinline__ unsigned f2bf(float f) {
    unsigned u = __float_as_uint(f);
    u += 0x7FFFu + ((u >> 16) & 1u);   // round-to-nearest-even
    return u >> 16;
}
__device__ __forceinline__ unsigned pk2(float lo, float hi) {
    return f2bf(lo) | (f2bf(hi) << 16);
}

// grid 512, block 256. bid: b = bid&7 (XCD-pinned), slice = (bid>>3)&31, th = bid>>8.
__global__ __launch_bounds__(256) void conv12_kernel(const float* __restrict__ x,
        const float* __restrict__ w0, const float* __restrict__ w1,
        const float* __restrict__ w2, const float* __restrict__ w3,
        const float* __restrict__ w4, const float* __restrict__ w5,
        const float* __restrict__ w6, float* __restrict__ out) {
    __shared__ uint4 ring[4][768];     // 4 slabs x 96 rows x 8 chunks = 48 KB
    int bid = blockIdx.x;
    int b = bid & 7;                   // batch = XCD (round-robin dispatch)
    int rc0 = ((bid >> 3) & 31) << 5;  // rc-slice base
    int t0 = (bid >> 8) << 4;          // t-half base: 0 or 16
    int tid = threadIdx.x;
    int lane = tid & 63;
    int wv = tid >> 6;                 // 0..3
    int lo = lane & 15;
    int quad = lane >> 4;
    int oh = wv & 1;                   // o-half (32 outputs)
    int rh = wv >> 1;                  // row-half (16 rows)
    const float* xb = x + (size_t)b * CIN * SB;

    // ---- B preload: fp32 w -> 28 bf16x8 frags in-register (112 VGPR) ----
    const float* wp[7] = {w0, w1, w2, w3, w4, w5, w6};
    bf16x8 bq[7][2][2];
#pragma unroll
    for (int tap = 0; tap < 7; ++tap)
#pragma unroll
        for (int ks = 0; ks < 2; ++ks)
#pragma unroll
            for (int nt = 0; nt < 2; ++nt) {
                const float* p = wp[tap] + (oh * 32 + nt * 16 + lo) * 64 + ks * 32 + quad * 8;
                float4 f0 = *(const float4*)p;
                float4 f1 = *(const float4*)(p + 4);
                uint4 v = make_uint4(pk2(f0.x, f0.y), pk2(f0.z, f0.w),
                                     pk2(f1.x, f1.y), pk2(f1.z, f1.w));
                bq[tap][ks][nt] = __builtin_bit_cast(bf16x8, v);
            }

    // lane geometry (t-invariant)
    int rc = rc0 + rh * 16 + lo;       // A-row rc in [0,1024)
    int rl = 32 + rh * 16 + lo;        // local slab row in [32,64)
    int r = rc >> 5;
    int c = rc & 31;
    bool okrm = (r > 0), okrp = (r < 31), okcm = (c > 0), okcp = (c < 31);

    // ---- staging: item = (2 rc-rows x 8 ch); thread owns item tid (+ item 256+tid if tid<128)
    // loads: 8 float2 per item along rc (64B segments per channel across the wave)
    int cg1 = tid & 7, s21 = tid >> 3;                 // item 1: rows 2*s21, +1
    int rx1 = rc0 - 32 + 2 * s21;
    rx1 = rx1 < 0 ? 0 : (rx1 > 1022 ? 1022 : rx1);     // even clamp; clamped rows masked-only
    int cg2 = tid & 7, s22 = 32 + (tid >> 3);          // item 2 (tid<128): rows 64..95
    int rx2 = rc0 - 32 + 2 * s22;
    rx2 = rx2 > 1022 ? 1022 : rx2;

    float2 va[8], vb[8];
    auto stage_load = [&](int ts) {
        const float* g1 = xb + (size_t)(cg1 * 8) * SB + ts * 1024 + rx1;
#pragma unroll
        for (int u = 0; u < 4; ++u) {
            va[u]     = *(const float2*)(g1 + (size_t)(2 * u) * SB);
            va[u + 4] = *(const float2*)(g1 + (size_t)(2 * u + 1) * SB);
        }
        if (tid < 128) {
            const float* g2 = xb + (size_t)(cg2 * 8) * SB + ts * 1024 + rx2;
#pragma unroll
            for (int u = 0; u < 4; ++u) {
                vb[u]     = *(const float2*)(g2 + (size_t)(2 * u) * SB);
                vb[u + 4] = *(const float2*)(g2 + (size_t)(2 * u + 1) * SB);
            }
        }
    };
    auto stage_write = [&](int ts) {
        int k = ts & 3;
        {
            int rw = 2 * s21;
            uint4 A = make_uint4(pk2(va[0].x, va[4].x), pk2(va[1].x, va[5].x),
                                 pk2(va[2].x, va[6].x), pk2(va[3].x, va[7].x));
            uint4 B = make_uint4(pk2(va[0].y, va[4].y), pk2(va[1].y, va[5].y),
                                 pk2(va[2].y, va[6].y), pk2(va[3].y, va[7].y));
            ring[k][rw * 8 + (cg1 ^ (rw & 7))] = A;
            ring[k][(rw + 1) * 8 + (cg1 ^ ((rw + 1) & 7))] = B;
        }
        if (tid < 128) {
            int rw = 2 * s22;
            uint4 A = make_uint4(pk2(vb[0].x, vb[4].x), pk2(vb[1].x, vb[5].x),
                                 pk2(vb[2].x, vb[6].x), pk2(vb[3].x, vb[7].x));
            uint4 B = make_uint4(pk2(vb[0].y, vb[4].y), pk2(vb[1].y, vb[5].y),
                                 pk2(vb[2].y, vb[6].y), pk2(vb[3].y, vb[7].y));
            ring[k][rw * 8 + (cg2 ^ (rw & 7))] = A;
            ring[k][(rw + 1) * 8 + (cg2 ^ ((rw + 1) & 7))] = B;
        }
    };

    const s16x8 zz = {0, 0, 0, 0, 0, 0, 0, 0};
    f32x4 aA0, aB0, aA1, aB1;          // 4 independent chains: [nt] x [ks]

    // one tap: 2 ds_read_b128 (shared by both nt tiles, f=2) + 4 MFMA
    auto tap_f = [&](const uint4* slab, const bf16x8 (&bt)[2][2], int d, bool ok) {
        int row = rl + d;                              // always in [0,96)
        s16x8 a0 = *((const s16x8*)slab + row * 8 + (quad ^ (row & 7)));
        s16x8 a1 = *((const s16x8*)slab + row * 8 + ((4 + quad) ^ (row & 7)));
        a0 = ok ? a0 : zz;
        a1 = ok ? a1 : zz;
        bf16x8 af0 = __builtin_bit_cast(bf16x8, a0);
        bf16x8 af1 = __builtin_bit_cast(bf16x8, a1);
        aA0 = __builtin_amdgcn_mfma_f32_16x16x32_bf16(af0, bt[0][0], aA0, 0, 0, 0);
        aB0 = __builtin_amdgcn_mfma_f32_16x16x32_bf16(af1, bt[1][0], aB0, 0, 0, 0);
        aA1 = __builtin_amdgcn_mfma_f32_16x16x32_bf16(af0, bt[0][1], aA1, 0, 0, 0);
        aB1 = __builtin_amdgcn_mfma_f32_16x16x32_bf16(af1, bt[1][1], aB1, 0, 0, 0);
    };

    int smax = (t0 == 0) ? 16 : 31;    // highest slab this block ever reads

    // ---- prologue: slabs t0-1 (th=1 only), t0, t0+1 staged; slab t0+2 in regs ----
    if (t0 > 0) { stage_load(t0 - 1); stage_write(t0 - 1); }
    stage_load(t0);     stage_write(t0);
    stage_load(t0 + 1); stage_write(t0 + 1);
    stage_load(t0 + 2);                // consumed at top of first loop iter
    asm volatile("s_waitcnt lgkmcnt(0)" ::: "memory");
    __builtin_amdgcn_s_barrier();
    __builtin_amdgcn_sched_barrier(0);

    for (int t = t0; t < t0 + 16; ++t) {
        // 1) publish slab t+2 (data loaded a full iteration ago -> latency covered)
        if (t + 2 <= smax) stage_write(t + 2);   // slot (t+2)&3=(t-2)&3: last read iter t-1
        // 2) issue loads for slab t+3 (consumed at top of iter t+1)
        if (t + 3 <= smax) stage_load(t + 3);

        // 3) compute from slabs t-1, t, t+1
        aA0 = (f32x4){0.f, 0.f, 0.f, 0.f};
        aB0 = (f32x4){0.f, 0.f, 0.f, 0.f};
        aA1 = (f32x4){0.f, 0.f, 0.f, 0.f};
        aB1 = (f32x4){0.f, 0.f, 0.f, 0.f};
        const uint4* s0 = &ring[t & 3][0];

        tap_f(s0, bq[0], 0, true);                             // self
        if (t > 0)  tap_f(&ring[(t - 1) & 3][0], bq[1], 0, true);   // t-1
        if (t < 31) tap_f(&ring[(t + 1) & 3][0], bq[2], 0, true);   // t+1
        tap_f(s0, bq[3], -32, okrm);                           // r-1
        tap_f(s0, bq[4], 32, okrp);                            // r+1
        tap_f(s0, bq[5], -1, okcm);                            // c-1
        tap_f(s0, bq[6], 1, okcp);                             // c+1

        // 4) store (never drained in-loop)
        f32x4 o0 = aA0 + aB0;
        f32x4 o1 = aA1 + aB1;
        size_t ob = ((size_t)(b * COUT + oh * 32 + lo)) * SB
                  + (size_t)t * 1024 + rc0 + rh * 16 + quad * 4;
        *(f32x4*)(out + ob) = o0;                  // nt = 0
        *(f32x4*)(out + ob + (size_t)16 * SB) = o1;    // nt = 1 (o += 16)

        // 5) close iteration: my ds ops retired, then block-wide publish
        asm volatile("s_waitcnt lgkmcnt(0)" ::: "memory");
        __builtin_amdgcn_s_barrier();
        __builtin_amdgcn_sched_barrier(0);
    }
}

extern "C" void kernel_launch(void* const* d_in, const int* in_sizes, int n_in,
                              void* d_out, int out_size, void* d_ws, size_t ws_size,
                              hipStream_t stream) {
    const float* x = (const float*)d_in[0];
    const float* w0 = (const float*)d_in[1];
    const float* w1 = (const float*)d_in[2];
    const float* w2 = (const float*)d_in[3];
    const float* w3 = (const float*)d_in[4];
    const float* w4 = (const float*)d_in[5];
    const float* w5 = (const float*)d_in[6];
    const float* w6 = (const float*)d_in[7];
    float* out = (float*)d_out;
    (void)d_ws; (void)ws_size;

    conv12_kernel<<<512, 256, 0, stream>>>(x, w0, w1, w2, w3, w4, w5, w6, out);
}